// Round 3
// baseline (24411.984 us; speedup 1.0000x reference)
//
#include <hip/hip_runtime.h>

// Echo State Network, T=1024 sequential steps of r' = 0.5 r + 0.5 tanh(W r + Win u).
// Persistent kernel, W pinned in VGPRs: 256 WG x 16 waves x 1 row, 64 VGPR of W/lane.
// Cross-WG step barrier via device-scope flags in d_ws.
//
// Round-3 changes (vs round-2 @ 24 ms):
//  * VGPR_Count stayed exactly 100 both rounds => backend's occupancy heuristic picked
//    its own waves/EU target (~5/EU ~= 100 regs) and SPILLED the W array to scratch;
//    launch_bounds min-waves only raises the cap, it doesn't stop that.
//    Fixes: (1) amdgpu_waves_per_eu(4,4) pins the occupancy target => budget exactly
//    128 regs, no spill incentive; (2) 1 row/wave (16 waves, 1024 thr) so W needs only
//    64 regs/lane, total pressure ~105 < 128.
//
// d_ws layout: [0, 32768): float rbuf[2][4096] (double-buffered r)
//              [32768, 33792): int flags[256]  (last published step per WG)

#define T_STEPS 1024
#define R_DIM   4096
#define N_WG    256
#define N_THR   1024
#define ROWS_PER_WG 16
#define K_CHUNKS 16          // R_DIM / (64 lanes * 4 floats)

#define AGENT __HIP_MEMORY_SCOPE_AGENT

__device__ __forceinline__ float fast_tanh(float x) {
    // tanh(x) = sign(x) * (1 - e) / (1 + e), e = exp(-2|x|).  v_exp_f32 inline, no call.
    float ax = fabsf(x);
    float e  = __expf(-2.0f * ax);
    float t  = (1.0f - e) / (1.0f + e);
    return copysignf(t, x);
}

__global__ void __launch_bounds__(N_THR)
__attribute__((amdgpu_waves_per_eu(4, 4)))
esn_persistent(const float* __restrict__ batch,
               const float* __restrict__ Win,
               const float* __restrict__ W,
               const float* __restrict__ Wout,
               float* __restrict__ out,
               float* __restrict__ rbuf,
               int*   __restrict__ flags)
{
    __shared__ __align__(16) float r_lds[R_DIM];   // current r(t), broadcast to all waves
    __shared__ float b_lds[T_STEPS];               // input sequence

    const int tid  = threadIdx.x;
    const int wid  = blockIdx.x;
    const int wave = tid >> 6;
    const int lane = tid & 63;
    const int row  = wid * ROWS_PER_WG + wave;     // this wave's single W row

    for (int i = tid; i < R_DIM; i += N_THR) r_lds[i] = 0.0f;   // r(0) = 0
    for (int i = tid; i < T_STEPS; i += N_THR) b_lds[i] = batch[i];

    // Pin this wave's W row in registers: lane holds float4 slice c at k = c*256 + lane*4.
    float4 wv[K_CHUNKS];
    {
        const float4* pW = reinterpret_cast<const float4*>(W + (size_t)row * R_DIM);
        #pragma unroll
        for (int c = 0; c < K_CHUNKS; ++c) wv[c] = pW[c * 64 + lane];
        // Forbid rematerialization: values become asm-defined, not load-defined.
        #pragma unroll
        for (int c = 0; c < K_CHUNKS; ++c)
            asm("" : "+v"(wv[c].x), "+v"(wv[c].y), "+v"(wv[c].z), "+v"(wv[c].w));
    }
    const float win0 = Win[2 * row], win1 = Win[2 * row + 1];

    __syncthreads();

    const float4* rv4 = reinterpret_cast<const float4*>(r_lds);

    for (int t = 0; t < T_STEPS; ++t) {
        if (t > 0) {
            // Wait until every WG has published r(t), then stage rbuf[t&1] -> LDS.
            if (tid < N_WG) {
                while (__hip_atomic_load(&flags[tid], __ATOMIC_ACQUIRE, AGENT) < t)
                    __builtin_amdgcn_s_sleep(1);
            }
            __syncthreads();
            const float* src = rbuf + (size_t)(t & 1) * R_DIM;
            #pragma unroll
            for (int j = 0; j < R_DIM / N_THR; ++j) {
                int i = tid + j * N_THR;   // coalesced, device-coherent loads
                r_lds[i] = __hip_atomic_load(src + i, __ATOMIC_RELAXED, AGENT);
            }
            __syncthreads();

            // pred[t-1] = Wout[0] + Wout[1]*b[t-1] + dot(Wout[2:], r(t))  (WG0 wave0 only,
            // runs concurrently with other waves' matvec; no barrier inside)
            if (wid == 0 && wave == 0) {
                const float* wr = Wout + 2;
                float s = 0.0f;
                #pragma unroll
                for (int c = 0; c < K_CHUNKS; ++c) {
                    int k = c * 256 + lane * 4;
                    float2 wa = *reinterpret_cast<const float2*>(wr + k);
                    float2 wb = *reinterpret_cast<const float2*>(wr + k + 2);
                    float4 rv = rv4[c * 64 + lane];
                    s = fmaf(wa.x, rv.x, s);
                    s = fmaf(wa.y, rv.y, s);
                    s = fmaf(wb.x, rv.z, s);
                    s = fmaf(wb.y, rv.w, s);
                }
                #pragma unroll
                for (int m = 1; m < 64; m <<= 1) s += __shfl_xor(s, m);
                if (lane == 0)
                    out[t - 1] = s + fmaf(Wout[1], b_lds[t - 1], Wout[0]);
            }
        }

        // y[row] = W[row,:] . r(t)  (W in registers, r broadcast from LDS).
        float4 a = make_float4(0.f, 0.f, 0.f, 0.f);
        #pragma unroll
        for (int c = 0; c < K_CHUNKS; ++c) {
            float4 rv = rv4[c * 64 + lane];
            a.x = fmaf(wv[c].x, rv.x, a.x);
            a.y = fmaf(wv[c].y, rv.y, a.y);
            a.z = fmaf(wv[c].z, rv.z, a.z);
            a.w = fmaf(wv[c].w, rv.w, a.w);
        }
        float s = (a.x + a.y) + (a.z + a.w);
        #pragma unroll
        for (int m = 1; m < 64; m <<= 1) s += __shfl_xor(s, m);

        if (lane == 0) {
            float bt = b_lds[t];
            float x  = fast_tanh(s + fmaf(win1, bt, win0));
            float rn = 0.5f * (r_lds[row] + x);   // (1-leak)*r + leak*x, leak=0.5
            float* dst = rbuf + (size_t)((t + 1) & 1) * R_DIM;
            __hip_atomic_store(dst + row, rn, __ATOMIC_RELAXED, AGENT);
        }
        __syncthreads();   // drains all waves' vmem stores before the flag release
        if (tid == 0)
            __hip_atomic_store(&flags[wid], t + 1, __ATOMIC_RELEASE, AGENT);
    }

    // Epilogue: pred[T-1] needs r(T); only WG0 participates (intra-WG barrier is fine).
    if (wid == 0) {
        if (tid < N_WG) {
            while (__hip_atomic_load(&flags[tid], __ATOMIC_ACQUIRE, AGENT) < T_STEPS)
                __builtin_amdgcn_s_sleep(1);
        }
        __syncthreads();
        const float* src = rbuf + (size_t)(T_STEPS & 1) * R_DIM;
        #pragma unroll
        for (int j = 0; j < R_DIM / N_THR; ++j) {
            int i = tid + j * N_THR;
            r_lds[i] = __hip_atomic_load(src + i, __ATOMIC_RELAXED, AGENT);
        }
        __syncthreads();
        if (wave == 0) {
            const float* wr = Wout + 2;
            float s = 0.0f;
            #pragma unroll
            for (int c = 0; c < K_CHUNKS; ++c) {
                int k = c * 256 + lane * 4;
                float2 wa = *reinterpret_cast<const float2*>(wr + k);
                float2 wb = *reinterpret_cast<const float2*>(wr + k + 2);
                float4 rv = rv4[c * 64 + lane];
                s = fmaf(wa.x, rv.x, s);
                s = fmaf(wa.y, rv.y, s);
                s = fmaf(wb.x, rv.z, s);
                s = fmaf(wb.y, rv.w, s);
            }
            #pragma unroll
            for (int m = 1; m < 64; m <<= 1) s += __shfl_xor(s, m);
            if (lane == 0)
                out[T_STEPS - 1] = s + fmaf(Wout[1], b_lds[T_STEPS - 1], Wout[0]);
        }
    }
}

extern "C" void kernel_launch(void* const* d_in, const int* in_sizes, int n_in,
                              void* d_out, int out_size, void* d_ws, size_t ws_size,
                              hipStream_t stream) {
    (void)in_sizes; (void)n_in; (void)out_size; (void)ws_size;
    const float* batch = (const float*)d_in[0];   // (1024,1,1)
    const float* Win   = (const float*)d_in[1];   // (4096,2) row-major
    const float* W     = (const float*)d_in[2];   // (4096,4096) row-major
    const float* Wout  = (const float*)d_in[3];   // (1,4098)
    float* out  = (float*)d_out;                  // (1024,1)
    float* rbuf = (float*)d_ws;                                   // 2*4096 floats
    int*   flags = (int*)((char*)d_ws + 2 * R_DIM * sizeof(float)); // 256 ints

    // flags must start < 1 every launch (d_ws is not re-poisoned between replays).
    hipMemsetAsync(flags, 0, N_WG * sizeof(int), stream);

    // grid=256 WGs, 1024 thr each (16 waves = 4 waves/SIMD, pinned by
    // amdgpu_waves_per_eu(4,4)); grid == CU count => all WGs co-resident
    // for the spin barrier.
    esn_persistent<<<dim3(N_WG), dim3(N_THR), 0, stream>>>(
        batch, Win, W, Wout, out, rbuf, flags);
}

// Round 4
// 22960.303 us; speedup vs baseline: 1.0632x; 1.0632x over previous
//
#include <hip/hip_runtime.h>

// Echo State Network, T=1024 sequential steps of r' = 0.5 r + 0.5 tanh(W r + Win u).
// Persistent kernel. W pinned in hard-named AGPRs: 256 WG x 8 waves x 2 rows,
// 128 floats/lane in physical a0..a127 via v_accvgpr_write_b32 (the register
// allocator cannot spill/remat what it only sees as asm clobbers).
//
// History: r1/r2 (VGPR array + asm laundering): allocator spilled W to scratch
// (VGPR_Count 100/64, WRITE_SIZE 281 MB cold, 24 ms = 64 MB/step from L3).
// r3 (waves_per_eu(4,4)): ignored, still 64 VGPRs. => hard AGPR pinning.
//
// d_ws layout: [0, 32768): float rbuf[2][4096] (double-buffered r)
//              [32768, 33792): int flags[256]  (last published step per WG)

#define T_STEPS 1024
#define R_DIM   4096
#define N_WG    256
#define N_THR   512
#define ROWS_PER_WG 16
#define K_CHUNKS 16          // R_DIM / (64 lanes * 4 floats)

#define AGENT __HIP_MEMORY_SCOPE_AGENT

__device__ __forceinline__ float fast_tanh(float x) {
    // tanh(x) = sign(x) * (1 - e) / (1 + e), e = exp(-2|x|).  v_exp_f32 inline, no call.
    float ax = fabsf(x);
    float e  = __expf(-2.0f * ax);
    float t  = (1.0f - e) / (1.0f + e);
    return copysignf(t, x);
}

// Store one float4 into four named physical AGPRs.
#define WST4(A0, A1, A2, A3, vec)                                              \
    asm volatile("v_accvgpr_write_b32 a" #A0 ", %0\n\t"                        \
                 "v_accvgpr_write_b32 a" #A1 ", %1\n\t"                        \
                 "v_accvgpr_write_b32 a" #A2 ", %2\n\t"                        \
                 "v_accvgpr_write_b32 a" #A3 ", %3"                            \
                 :: "v"((vec).x), "v"((vec).y), "v"((vec).z), "v"((vec).w)     \
                 : "a" #A0, "a" #A1, "a" #A2, "a" #A3)

// One K-chunk of the two-row matvec: read 4+4 W values from AGPRs, FMA with rv.
#define MV2(c, A0, A1, A2, A3, B0, B1, B2, B3)                                 \
    do {                                                                       \
        float4 rv = rv4[(c) * 64 + lane];                                      \
        float w0, w1, w2, w3, u0, u1, u2, u3;                                  \
        asm volatile("v_accvgpr_read_b32 %0, a" #A0 "\n\t"                     \
                     "v_accvgpr_read_b32 %1, a" #A1 "\n\t"                     \
                     "v_accvgpr_read_b32 %2, a" #A2 "\n\t"                     \
                     "v_accvgpr_read_b32 %3, a" #A3 "\n\t"                     \
                     "v_accvgpr_read_b32 %4, a" #B0 "\n\t"                     \
                     "v_accvgpr_read_b32 %5, a" #B1 "\n\t"                     \
                     "v_accvgpr_read_b32 %6, a" #B2 "\n\t"                     \
                     "v_accvgpr_read_b32 %7, a" #B3                            \
                     : "=v"(w0), "=v"(w1), "=v"(w2), "=v"(w3),                 \
                       "=v"(u0), "=v"(u1), "=v"(u2), "=v"(u3));                \
        accA.x = fmaf(w0, rv.x, accA.x);                                       \
        accA.y = fmaf(w1, rv.y, accA.y);                                       \
        accA.z = fmaf(w2, rv.z, accA.z);                                       \
        accA.w = fmaf(w3, rv.w, accA.w);                                       \
        accB.x = fmaf(u0, rv.x, accB.x);                                       \
        accB.y = fmaf(u1, rv.y, accB.y);                                       \
        accB.z = fmaf(u2, rv.z, accB.z);                                       \
        accB.w = fmaf(u3, rv.w, accB.w);                                       \
    } while (0)

__global__ __launch_bounds__(N_THR, 2)
void esn_persistent(const float* __restrict__ batch,
                    const float* __restrict__ Win,
                    const float* __restrict__ W,
                    const float* __restrict__ Wout,
                    float* __restrict__ out,
                    float* __restrict__ rbuf,
                    int*   __restrict__ flags)
{
    __shared__ __align__(16) float r_lds[R_DIM];   // current r(t), broadcast to all waves
    __shared__ float b_lds[T_STEPS];               // input sequence

    const int tid  = threadIdx.x;
    const int wid  = blockIdx.x;
    const int wave = tid >> 6;
    const int lane = tid & 63;
    const int rowA = wid * ROWS_PER_WG + wave * 2; // this wave's two W rows
    const int rowB = rowA + 1;

    for (int i = tid; i < R_DIM; i += N_THR) r_lds[i] = 0.0f;   // r(0) = 0
    for (int i = tid; i < T_STEPS; i += N_THR) b_lds[i] = batch[i];

    // Pin W rows in physical AGPRs. Lane's chunk c covers k = c*256 + lane*4.
    // Row A -> a0..a63 (chunk c -> a[4c..4c+3]); row B -> a64..a127.
    {
        const float4* pA = reinterpret_cast<const float4*>(W + (size_t)rowA * R_DIM);
        const float4* pB = reinterpret_cast<const float4*>(W + (size_t)rowB * R_DIM);
        float4 v;
        v = pA[ 0 * 64 + lane]; WST4(  0,   1,   2,   3, v);
        v = pA[ 1 * 64 + lane]; WST4(  4,   5,   6,   7, v);
        v = pA[ 2 * 64 + lane]; WST4(  8,   9,  10,  11, v);
        v = pA[ 3 * 64 + lane]; WST4( 12,  13,  14,  15, v);
        v = pA[ 4 * 64 + lane]; WST4( 16,  17,  18,  19, v);
        v = pA[ 5 * 64 + lane]; WST4( 20,  21,  22,  23, v);
        v = pA[ 6 * 64 + lane]; WST4( 24,  25,  26,  27, v);
        v = pA[ 7 * 64 + lane]; WST4( 28,  29,  30,  31, v);
        v = pA[ 8 * 64 + lane]; WST4( 32,  33,  34,  35, v);
        v = pA[ 9 * 64 + lane]; WST4( 36,  37,  38,  39, v);
        v = pA[10 * 64 + lane]; WST4( 40,  41,  42,  43, v);
        v = pA[11 * 64 + lane]; WST4( 44,  45,  46,  47, v);
        v = pA[12 * 64 + lane]; WST4( 48,  49,  50,  51, v);
        v = pA[13 * 64 + lane]; WST4( 52,  53,  54,  55, v);
        v = pA[14 * 64 + lane]; WST4( 56,  57,  58,  59, v);
        v = pA[15 * 64 + lane]; WST4( 60,  61,  62,  63, v);
        v = pB[ 0 * 64 + lane]; WST4( 64,  65,  66,  67, v);
        v = pB[ 1 * 64 + lane]; WST4( 68,  69,  70,  71, v);
        v = pB[ 2 * 64 + lane]; WST4( 72,  73,  74,  75, v);
        v = pB[ 3 * 64 + lane]; WST4( 76,  77,  78,  79, v);
        v = pB[ 4 * 64 + lane]; WST4( 80,  81,  82,  83, v);
        v = pB[ 5 * 64 + lane]; WST4( 84,  85,  86,  87, v);
        v = pB[ 6 * 64 + lane]; WST4( 88,  89,  90,  91, v);
        v = pB[ 7 * 64 + lane]; WST4( 92,  93,  94,  95, v);
        v = pB[ 8 * 64 + lane]; WST4( 96,  97,  98,  99, v);
        v = pB[ 9 * 64 + lane]; WST4(100, 101, 102, 103, v);
        v = pB[10 * 64 + lane]; WST4(104, 105, 106, 107, v);
        v = pB[11 * 64 + lane]; WST4(108, 109, 110, 111, v);
        v = pB[12 * 64 + lane]; WST4(112, 113, 114, 115, v);
        v = pB[13 * 64 + lane]; WST4(116, 117, 118, 119, v);
        v = pB[14 * 64 + lane]; WST4(120, 121, 122, 123, v);
        v = pB[15 * 64 + lane]; WST4(124, 125, 126, 127, v);
    }
    const float winA0 = Win[2 * rowA], winA1 = Win[2 * rowA + 1];
    const float winB0 = Win[2 * rowB], winB1 = Win[2 * rowB + 1];

    __syncthreads();

    const float4* rv4 = reinterpret_cast<const float4*>(r_lds);

    for (int t = 0; t < T_STEPS; ++t) {
        if (t > 0) {
            // Wait until every WG has published r(t), then stage rbuf[t&1] -> LDS.
            if (tid < N_WG) {
                while (__hip_atomic_load(&flags[tid], __ATOMIC_ACQUIRE, AGENT) < t)
                    __builtin_amdgcn_s_sleep(1);
            }
            __syncthreads();
            const float* src = rbuf + (size_t)(t & 1) * R_DIM;
            #pragma unroll
            for (int j = 0; j < R_DIM / N_THR; ++j) {
                int i = tid + j * N_THR;   // coalesced, device-coherent loads
                r_lds[i] = __hip_atomic_load(src + i, __ATOMIC_RELAXED, AGENT);
            }
            __syncthreads();

            // pred[t-1] = Wout[0] + Wout[1]*b[t-1] + dot(Wout[2:], r(t))  (WG0 wave0,
            // concurrent with other waves' matvec; no barrier inside)
            if (wid == 0 && wave == 0) {
                const float* wr = Wout + 2;
                float s = 0.0f;
                #pragma unroll
                for (int c = 0; c < K_CHUNKS; ++c) {
                    int k = c * 256 + lane * 4;
                    float2 wa = *reinterpret_cast<const float2*>(wr + k);
                    float2 wb = *reinterpret_cast<const float2*>(wr + k + 2);
                    float4 rv = rv4[c * 64 + lane];
                    s = fmaf(wa.x, rv.x, s);
                    s = fmaf(wa.y, rv.y, s);
                    s = fmaf(wb.x, rv.z, s);
                    s = fmaf(wb.y, rv.w, s);
                }
                #pragma unroll
                for (int m = 1; m < 64; m <<= 1) s += __shfl_xor(s, m);
                if (lane == 0)
                    out[t - 1] = s + fmaf(Wout[1], b_lds[t - 1], Wout[0]);
            }
        }

        // y = W r(t) for this wave's two rows (W in AGPRs, r broadcast from LDS).
        float4 accA = make_float4(0.f, 0.f, 0.f, 0.f);
        float4 accB = make_float4(0.f, 0.f, 0.f, 0.f);
        MV2( 0,   0,   1,   2,   3,  64,  65,  66,  67);
        MV2( 1,   4,   5,   6,   7,  68,  69,  70,  71);
        MV2( 2,   8,   9,  10,  11,  72,  73,  74,  75);
        MV2( 3,  12,  13,  14,  15,  76,  77,  78,  79);
        MV2( 4,  16,  17,  18,  19,  80,  81,  82,  83);
        MV2( 5,  20,  21,  22,  23,  84,  85,  86,  87);
        MV2( 6,  24,  25,  26,  27,  88,  89,  90,  91);
        MV2( 7,  28,  29,  30,  31,  92,  93,  94,  95);
        MV2( 8,  32,  33,  34,  35,  96,  97,  98,  99);
        MV2( 9,  36,  37,  38,  39, 100, 101, 102, 103);
        MV2(10,  40,  41,  42,  43, 104, 105, 106, 107);
        MV2(11,  44,  45,  46,  47, 108, 109, 110, 111);
        MV2(12,  48,  49,  50,  51, 112, 113, 114, 115);
        MV2(13,  52,  53,  54,  55, 116, 117, 118, 119);
        MV2(14,  56,  57,  58,  59, 120, 121, 122, 123);
        MV2(15,  60,  61,  62,  63, 124, 125, 126, 127);

        float sA = (accA.x + accA.y) + (accA.z + accA.w);
        float sB = (accB.x + accB.y) + (accB.z + accB.w);
        #pragma unroll
        for (int m = 1; m < 64; m <<= 1) {
            sA += __shfl_xor(sA, m);
            sB += __shfl_xor(sB, m);
        }

        if (lane == 0) {
            float bt = b_lds[t];
            float xA = fast_tanh(sA + fmaf(winA1, bt, winA0));
            float xB = fast_tanh(sB + fmaf(winB1, bt, winB0));
            float rnA = 0.5f * (r_lds[rowA] + xA);   // (1-leak)*r + leak*x, leak=0.5
            float rnB = 0.5f * (r_lds[rowB] + xB);
            float* dst = rbuf + (size_t)((t + 1) & 1) * R_DIM;
            __hip_atomic_store(dst + rowA, rnA, __ATOMIC_RELAXED, AGENT);
            __hip_atomic_store(dst + rowB, rnB, __ATOMIC_RELAXED, AGENT);
        }
        __syncthreads();   // drains all waves' vmem stores before the flag release
        if (tid == 0)
            __hip_atomic_store(&flags[wid], t + 1, __ATOMIC_RELEASE, AGENT);
    }

    // Epilogue: pred[T-1] needs r(T); only WG0 participates (intra-WG barrier is fine).
    if (wid == 0) {
        if (tid < N_WG) {
            while (__hip_atomic_load(&flags[tid], __ATOMIC_ACQUIRE, AGENT) < T_STEPS)
                __builtin_amdgcn_s_sleep(1);
        }
        __syncthreads();
        const float* src = rbuf + (size_t)(T_STEPS & 1) * R_DIM;
        #pragma unroll
        for (int j = 0; j < R_DIM / N_THR; ++j) {
            int i = tid + j * N_THR;
            r_lds[i] = __hip_atomic_load(src + i, __ATOMIC_RELAXED, AGENT);
        }
        __syncthreads();
        if (wave == 0) {
            const float* wr = Wout + 2;
            float s = 0.0f;
            #pragma unroll
            for (int c = 0; c < K_CHUNKS; ++c) {
                int k = c * 256 + lane * 4;
                float2 wa = *reinterpret_cast<const float2*>(wr + k);
                float2 wb = *reinterpret_cast<const float2*>(wr + k + 2);
                float4 rv = rv4[c * 64 + lane];
                s = fmaf(wa.x, rv.x, s);
                s = fmaf(wa.y, rv.y, s);
                s = fmaf(wb.x, rv.z, s);
                s = fmaf(wb.y, rv.w, s);
            }
            #pragma unroll
            for (int m = 1; m < 64; m <<= 1) s += __shfl_xor(s, m);
            if (lane == 0)
                out[T_STEPS - 1] = s + fmaf(Wout[1], b_lds[T_STEPS - 1], Wout[0]);
        }
    }
}

extern "C" void kernel_launch(void* const* d_in, const int* in_sizes, int n_in,
                              void* d_out, int out_size, void* d_ws, size_t ws_size,
                              hipStream_t stream) {
    (void)in_sizes; (void)n_in; (void)out_size; (void)ws_size;
    const float* batch = (const float*)d_in[0];   // (1024,1,1)
    const float* Win   = (const float*)d_in[1];   // (4096,2) row-major
    const float* W     = (const float*)d_in[2];   // (4096,4096) row-major
    const float* Wout  = (const float*)d_in[3];   // (1,4098)
    float* out  = (float*)d_out;                  // (1024,1)
    float* rbuf = (float*)d_ws;                                   // 2*4096 floats
    int*   flags = (int*)((char*)d_ws + 2 * R_DIM * sizeof(float)); // 256 ints

    // flags must start < 1 every launch (d_ws is not re-poisoned between replays).
    hipMemsetAsync(flags, 0, N_WG * sizeof(int), stream);

    // grid=256 WGs x 512 thr (8 waves = 2 waves/SIMD; ~192 total regs/lane incl.
    // 128 AGPRs => fits 2/SIMD with slack). grid == CU count => all WGs co-resident
    // for the spin barrier.
    esn_persistent<<<dim3(N_WG), dim3(N_THR), 0, stream>>>(
        batch, Win, W, Wout, out, rbuf, flags);
}

// Round 5
// 4085.865 us; speedup vs baseline: 5.9747x; 5.6194x over previous
//
#include <hip/hip_runtime.h>

// Echo State Network, T=1024 sequential steps of r' = 0.5 r + 0.5 tanh(W r + Win u).
// Persistent kernel. W pinned in hard-named AGPRs (r4, verified VGPR_Count=128).
//
// Round-5 change: r1-r4 all ~23-25 ms regardless of where W lived => sync-bound,
// not W-bound. The acquire/release agent atomics emit L2 cache-maintenance
// (buffer_inv per acquire-POLL-iteration, write-drain per release) on the
// non-cross-coherent per-XCD L2s — thousands of L2 invalidates per step.
// Fix: relaxed-only atomics (ordering from the vmcnt(0) drain __syncthreads
// already does), 8-B paired flag polls + paired rbuf stores/loads, polling on
// waves 4-5, pred moved off the critical path (after flag publish).
//
// d_ws layout: [0, 32768): float rbuf[2][4096] (double-buffered r)
//              [32768, 33792): int flags[256]  (last published step per WG)

#define T_STEPS 1024
#define R_DIM   4096
#define N_WG    256
#define N_THR   512
#define ROWS_PER_WG 16
#define K_CHUNKS 16          // R_DIM / (64 lanes * 4 floats)

#define AGENT __HIP_MEMORY_SCOPE_AGENT

typedef unsigned long long ull;

__device__ __forceinline__ float fast_tanh(float x) {
    float ax = fabsf(x);
    float e  = __expf(-2.0f * ax);
    float t  = (1.0f - e) / (1.0f + e);
    return copysignf(t, x);
}

// Store one float4 into four named physical AGPRs.
#define WST4(A0, A1, A2, A3, vec)                                              \
    asm volatile("v_accvgpr_write_b32 a" #A0 ", %0\n\t"                        \
                 "v_accvgpr_write_b32 a" #A1 ", %1\n\t"                        \
                 "v_accvgpr_write_b32 a" #A2 ", %2\n\t"                        \
                 "v_accvgpr_write_b32 a" #A3 ", %3"                            \
                 :: "v"((vec).x), "v"((vec).y), "v"((vec).z), "v"((vec).w)     \
                 : "a" #A0, "a" #A1, "a" #A2, "a" #A3)

// One K-chunk of the two-row matvec: read 4+4 W values from AGPRs, FMA with rv.
#define MV2(c, A0, A1, A2, A3, B0, B1, B2, B3)                                 \
    do {                                                                       \
        float4 rv = rv4[(c) * 64 + lane];                                      \
        float w0, w1, w2, w3, u0, u1, u2, u3;                                  \
        asm volatile("v_accvgpr_read_b32 %0, a" #A0 "\n\t"                     \
                     "v_accvgpr_read_b32 %1, a" #A1 "\n\t"                     \
                     "v_accvgpr_read_b32 %2, a" #A2 "\n\t"                     \
                     "v_accvgpr_read_b32 %3, a" #A3 "\n\t"                     \
                     "v_accvgpr_read_b32 %4, a" #B0 "\n\t"                     \
                     "v_accvgpr_read_b32 %5, a" #B1 "\n\t"                     \
                     "v_accvgpr_read_b32 %6, a" #B2 "\n\t"                     \
                     "v_accvgpr_read_b32 %7, a" #B3                            \
                     : "=v"(w0), "=v"(w1), "=v"(w2), "=v"(w3),                 \
                       "=v"(u0), "=v"(u1), "=v"(u2), "=v"(u3));                \
        accA.x = fmaf(w0, rv.x, accA.x);                                       \
        accA.y = fmaf(w1, rv.y, accA.y);                                       \
        accA.z = fmaf(w2, rv.z, accA.z);                                       \
        accA.w = fmaf(w3, rv.w, accA.w);                                       \
        accB.x = fmaf(u0, rv.x, accB.x);                                       \
        accB.y = fmaf(u1, rv.y, accB.y);                                       \
        accB.z = fmaf(u2, rv.z, accB.z);                                       \
        accB.w = fmaf(u3, rv.w, accB.w);                                       \
    } while (0)

__global__ __launch_bounds__(N_THR, 2)
void esn_persistent(const float* __restrict__ batch,
                    const float* __restrict__ Win,
                    const float* __restrict__ W,
                    const float* __restrict__ Wout,
                    float* __restrict__ out,
                    float* __restrict__ rbuf,
                    int*   __restrict__ flags)
{
    __shared__ __align__(16) float r_lds[R_DIM];   // current r(t)
    __shared__ float b_lds[T_STEPS];               // input sequence

    const int tid  = threadIdx.x;
    const int wid  = blockIdx.x;
    const int wave = tid >> 6;
    const int lane = tid & 63;
    const int rowA = wid * ROWS_PER_WG + wave * 2; // this wave's two W rows
    const int rowB = rowA + 1;

    for (int i = tid; i < R_DIM; i += N_THR) r_lds[i] = 0.0f;   // r(0) = 0
    for (int i = tid; i < T_STEPS; i += N_THR) b_lds[i] = batch[i];

    // Pin W rows in physical AGPRs. Lane's chunk c covers k = c*256 + lane*4.
    {
        const float4* pA = reinterpret_cast<const float4*>(W + (size_t)rowA * R_DIM);
        const float4* pB = reinterpret_cast<const float4*>(W + (size_t)rowB * R_DIM);
        float4 v;
        v = pA[ 0 * 64 + lane]; WST4(  0,   1,   2,   3, v);
        v = pA[ 1 * 64 + lane]; WST4(  4,   5,   6,   7, v);
        v = pA[ 2 * 64 + lane]; WST4(  8,   9,  10,  11, v);
        v = pA[ 3 * 64 + lane]; WST4( 12,  13,  14,  15, v);
        v = pA[ 4 * 64 + lane]; WST4( 16,  17,  18,  19, v);
        v = pA[ 5 * 64 + lane]; WST4( 20,  21,  22,  23, v);
        v = pA[ 6 * 64 + lane]; WST4( 24,  25,  26,  27, v);
        v = pA[ 7 * 64 + lane]; WST4( 28,  29,  30,  31, v);
        v = pA[ 8 * 64 + lane]; WST4( 32,  33,  34,  35, v);
        v = pA[ 9 * 64 + lane]; WST4( 36,  37,  38,  39, v);
        v = pA[10 * 64 + lane]; WST4( 40,  41,  42,  43, v);
        v = pA[11 * 64 + lane]; WST4( 44,  45,  46,  47, v);
        v = pA[12 * 64 + lane]; WST4( 48,  49,  50,  51, v);
        v = pA[13 * 64 + lane]; WST4( 52,  53,  54,  55, v);
        v = pA[14 * 64 + lane]; WST4( 56,  57,  58,  59, v);
        v = pA[15 * 64 + lane]; WST4( 60,  61,  62,  63, v);
        v = pB[ 0 * 64 + lane]; WST4( 64,  65,  66,  67, v);
        v = pB[ 1 * 64 + lane]; WST4( 68,  69,  70,  71, v);
        v = pB[ 2 * 64 + lane]; WST4( 72,  73,  74,  75, v);
        v = pB[ 3 * 64 + lane]; WST4( 76,  77,  78,  79, v);
        v = pB[ 4 * 64 + lane]; WST4( 80,  81,  82,  83, v);
        v = pB[ 5 * 64 + lane]; WST4( 84,  85,  86,  87, v);
        v = pB[ 6 * 64 + lane]; WST4( 88,  89,  90,  91, v);
        v = pB[ 7 * 64 + lane]; WST4( 92,  93,  94,  95, v);
        v = pB[ 8 * 64 + lane]; WST4( 96,  97,  98,  99, v);
        v = pB[ 9 * 64 + lane]; WST4(100, 101, 102, 103, v);
        v = pB[10 * 64 + lane]; WST4(104, 105, 106, 107, v);
        v = pB[11 * 64 + lane]; WST4(108, 109, 110, 111, v);
        v = pB[12 * 64 + lane]; WST4(112, 113, 114, 115, v);
        v = pB[13 * 64 + lane]; WST4(116, 117, 118, 119, v);
        v = pB[14 * 64 + lane]; WST4(120, 121, 122, 123, v);
        v = pB[15 * 64 + lane]; WST4(124, 125, 126, 127, v);
    }
    const float winA0 = Win[2 * rowA], winA1 = Win[2 * rowA + 1];
    const float winB0 = Win[2 * rowB], winB1 = Win[2 * rowB + 1];

    __syncthreads();

    const float4* rv4 = reinterpret_cast<const float4*>(r_lds);
    const ull* flags8 = reinterpret_cast<const ull*>(flags);
    ull* r_lds8 = reinterpret_cast<ull*>(r_lds);

    for (int t = 0; t < T_STEPS; ++t) {
        if (t > 0) {
            // Waves 4-5 poll flag PAIRS (relaxed — no L2 invalidate per poll).
            if (tid >= 256 && tid < 256 + 128) {
                const ull* fp = flags8 + (tid - 256);
                for (;;) {
                    ull v = __hip_atomic_load(fp, __ATOMIC_RELAXED, AGENT);
                    unsigned lo = (unsigned)v, hi = (unsigned)(v >> 32);
                    if ((int)lo >= t && (int)hi >= t) break;
                    __builtin_amdgcn_s_sleep(1);
                }
            }
            __syncthreads();
            // Stage rbuf[t&1] -> LDS as 8-B relaxed loads (4 per thread, coalesced).
            const ull* src8 = reinterpret_cast<const ull*>(rbuf + (size_t)(t & 1) * R_DIM);
            #pragma unroll
            for (int j = 0; j < (R_DIM / 2) / N_THR; ++j) {
                int i = tid + j * N_THR;
                r_lds8[i] = __hip_atomic_load(src8 + i, __ATOMIC_RELAXED, AGENT);
            }
            __syncthreads();
        }

        // y = W r(t) for this wave's two rows (W in AGPRs, r broadcast from LDS).
        float4 accA = make_float4(0.f, 0.f, 0.f, 0.f);
        float4 accB = make_float4(0.f, 0.f, 0.f, 0.f);
        MV2( 0,   0,   1,   2,   3,  64,  65,  66,  67);
        MV2( 1,   4,   5,   6,   7,  68,  69,  70,  71);
        MV2( 2,   8,   9,  10,  11,  72,  73,  74,  75);
        MV2( 3,  12,  13,  14,  15,  76,  77,  78,  79);
        MV2( 4,  16,  17,  18,  19,  80,  81,  82,  83);
        MV2( 5,  20,  21,  22,  23,  84,  85,  86,  87);
        MV2( 6,  24,  25,  26,  27,  88,  89,  90,  91);
        MV2( 7,  28,  29,  30,  31,  92,  93,  94,  95);
        MV2( 8,  32,  33,  34,  35,  96,  97,  98,  99);
        MV2( 9,  36,  37,  38,  39, 100, 101, 102, 103);
        MV2(10,  40,  41,  42,  43, 104, 105, 106, 107);
        MV2(11,  44,  45,  46,  47, 108, 109, 110, 111);
        MV2(12,  48,  49,  50,  51, 112, 113, 114, 115);
        MV2(13,  52,  53,  54,  55, 116, 117, 118, 119);
        MV2(14,  56,  57,  58,  59, 120, 121, 122, 123);
        MV2(15,  60,  61,  62,  63, 124, 125, 126, 127);

        float sA = (accA.x + accA.y) + (accA.z + accA.w);
        float sB = (accB.x + accB.y) + (accB.z + accB.w);
        #pragma unroll
        for (int m = 1; m < 64; m <<= 1) {
            sA += __shfl_xor(sA, m);
            sB += __shfl_xor(sB, m);
        }

        if (lane == 0) {
            float bt = b_lds[t];
            float xA = fast_tanh(sA + fmaf(winA1, bt, winA0));
            float xB = fast_tanh(sB + fmaf(winB1, bt, winB0));
            float rnA = 0.5f * (r_lds[rowA] + xA);
            float rnB = 0.5f * (r_lds[rowB] + xB);
            // rowA even -> 8-B aligned paired store of (rnA, rnB).
            ull pack = ((ull)__float_as_uint(rnB) << 32) | __float_as_uint(rnA);
            ull* dst = reinterpret_cast<ull*>(rbuf + (size_t)((t + 1) & 1) * R_DIM) + (rowA >> 1);
            __hip_atomic_store(dst, pack, __ATOMIC_RELAXED, AGENT);
        }
        __syncthreads();   // vmcnt(0) drain: paired stores committed before flag publish
        if (tid == 0)
            __hip_atomic_store(&flags[wid], t + 1, __ATOMIC_RELAXED, AGENT);

        // pred[t-1] off the critical path (after publish). Uses r_lds = r(t); other
        // waves can't overwrite r_lds until wave 0 reaches next staging barrier.
        if (wid == 0 && wave == 0 && t > 0) {
            const float* wr = Wout + 2;
            float s = 0.0f;
            #pragma unroll
            for (int c = 0; c < K_CHUNKS; ++c) {
                int k = c * 256 + lane * 4;
                float2 wa = *reinterpret_cast<const float2*>(wr + k);
                float2 wb = *reinterpret_cast<const float2*>(wr + k + 2);
                float4 rv = rv4[c * 64 + lane];
                s = fmaf(wa.x, rv.x, s);
                s = fmaf(wa.y, rv.y, s);
                s = fmaf(wb.x, rv.z, s);
                s = fmaf(wb.y, rv.w, s);
            }
            #pragma unroll
            for (int m = 1; m < 64; m <<= 1) s += __shfl_xor(s, m);
            if (lane == 0)
                out[t - 1] = s + fmaf(Wout[1], b_lds[t - 1], Wout[0]);
        }
    }

    // Epilogue: pred[T-1] needs r(T); only WG0 participates.
    if (wid == 0) {
        if (tid < 128) {
            const ull* fp = flags8 + tid;
            for (;;) {
                ull v = __hip_atomic_load(fp, __ATOMIC_RELAXED, AGENT);
                unsigned lo = (unsigned)v, hi = (unsigned)(v >> 32);
                if ((int)lo >= T_STEPS && (int)hi >= T_STEPS) break;
                __builtin_amdgcn_s_sleep(1);
            }
        }
        __syncthreads();
        const ull* src8 = reinterpret_cast<const ull*>(rbuf + (size_t)(T_STEPS & 1) * R_DIM);
        #pragma unroll
        for (int j = 0; j < (R_DIM / 2) / N_THR; ++j) {
            int i = tid + j * N_THR;
            r_lds8[i] = __hip_atomic_load(src8 + i, __ATOMIC_RELAXED, AGENT);
        }
        __syncthreads();
        if (wave == 0) {
            const float* wr = Wout + 2;
            float s = 0.0f;
            #pragma unroll
            for (int c = 0; c < K_CHUNKS; ++c) {
                int k = c * 256 + lane * 4;
                float2 wa = *reinterpret_cast<const float2*>(wr + k);
                float2 wb = *reinterpret_cast<const float2*>(wr + k + 2);
                float4 rv = rv4[c * 64 + lane];
                s = fmaf(wa.x, rv.x, s);
                s = fmaf(wa.y, rv.y, s);
                s = fmaf(wb.x, rv.z, s);
                s = fmaf(wb.y, rv.w, s);
            }
            #pragma unroll
            for (int m = 1; m < 64; m <<= 1) s += __shfl_xor(s, m);
            if (lane == 0)
                out[T_STEPS - 1] = s + fmaf(Wout[1], b_lds[T_STEPS - 1], Wout[0]);
        }
    }
}

extern "C" void kernel_launch(void* const* d_in, const int* in_sizes, int n_in,
                              void* d_out, int out_size, void* d_ws, size_t ws_size,
                              hipStream_t stream) {
    (void)in_sizes; (void)n_in; (void)out_size; (void)ws_size;
    const float* batch = (const float*)d_in[0];   // (1024,1,1)
    const float* Win   = (const float*)d_in[1];   // (4096,2) row-major
    const float* W     = (const float*)d_in[2];   // (4096,4096) row-major
    const float* Wout  = (const float*)d_in[3];   // (1,4098)
    float* out  = (float*)d_out;                  // (1024,1)
    float* rbuf = (float*)d_ws;                                   // 2*4096 floats
    int*   flags = (int*)((char*)d_ws + 2 * R_DIM * sizeof(float)); // 256 ints

    // flags must start < 1 every launch (d_ws is not re-poisoned between replays).
    hipMemsetAsync(flags, 0, N_WG * sizeof(int), stream);

    // grid=256 WGs x 512 thr (8 waves = 2 waves/SIMD; 128 AGPR + ~64 VGPR fits).
    // grid == CU count => all WGs co-resident for the spin barrier.
    esn_persistent<<<dim3(N_WG), dim3(N_THR), 0, stream>>>(
        batch, Win, W, Wout, out, rbuf, flags);
}